// Round 2
// baseline (463.044 us; speedup 1.0000x reference)
//
#include <hip/hip_runtime.h>

// Problem constants (from setup_inputs): B=16, C_img=3, H=448, W=1024.
#define BB 16
#define HH 448
#define WW 1024
constexpr int HW    = HH * WW;          // 458752
constexpr int TOTAL = BB * HW;          // 7340032
constexpr int NPX   = 4;                // pixels per thread (one aligned float4)
constexpr int NTHR  = 256;
constexpr int NBLK  = TOTAL / (NPX * NTHR);  // 7168

__global__ __launch_bounds__(NTHR) void elbo_main(
    const float* __restrict__ mean, const float* __restrict__ lv,
    const float* __restrict__ img1, const float* __restrict__ img2,
    const float* __restrict__ target, const float* __restrict__ eps,
    float2* __restrict__ partials)
{
    const int t  = blockIdx.x * NTHR + threadIdx.x;
    const int p4 = t * NPX;                 // first pixel of this thread's quad
    const int b  = p4 / HW;
    const int r  = p4 - b * HW;             // y*W + x, x % 4 == 0
    const int y  = r >> 10;                 // W = 1024
    const int x  = r & (WW - 1);
    const int base = b * 2 * HW + r;        // ch-0 index into (B,2,H,W) arrays

    // ---- bulk vector loads (all independent; issued up front) ----
    const float4 m0 = *(const float4*)(mean   + base);
    const float4 m1 = *(const float4*)(mean   + base + HW);
    const float4 l0 = *(const float4*)(lv     + base);
    const float4 l1 = *(const float4*)(lv     + base + HW);
    const float4 e0 = *(const float4*)(eps    + base);
    const float4 e1 = *(const float4*)(eps    + base + HW);
    const float4 t0 = *(const float4*)(target + base);
    const float4 t1 = *(const float4*)(target + base + HW);

    const int b3 = b * 3 * HW;
    const float4 i1c0 = *(const float4*)(img1 + b3 + r);
    const float4 i1c1 = *(const float4*)(img1 + b3 + HW + r);
    const float4 i1c2 = *(const float4*)(img1 + b3 + 2 * HW + r);

    const bool has_d = (y < HH - 1);
    float4 md0, md1, ld0, ld1, ed0, ed1;
    if (has_d) {
        md0 = *(const float4*)(mean + base + WW);
        md1 = *(const float4*)(mean + base + HW + WW);
        ld0 = *(const float4*)(lv   + base + WW);
        ld1 = *(const float4*)(lv   + base + HW + WW);
        ed0 = *(const float4*)(eps  + base + WW);
        ed1 = *(const float4*)(eps  + base + HW + WW);
    }

    const bool has_r = (x + NPX < WW);
    float m0r = 0.f, m1r = 0.f, l0r = 0.f, l1r = 0.f, e0r = 0.f, e1r = 0.f;
    if (has_r) {
        m0r = mean[base + 4];  m1r = mean[base + HW + 4];
        l0r = lv[base + 4];    l1r = lv[base + HW + 4];
        e0r = eps[base + 4];   e1r = eps[base + HW + 4];
    }

    // ---- flow samples ----
    float u[5], v[5], ud[4], vd[4];
    {
        const float* M0 = &m0.x; const float* M1 = &m1.x;
        const float* L0 = &l0.x; const float* L1 = &l1.x;
        const float* E0 = &e0.x; const float* E1 = &e1.x;
        #pragma unroll
        for (int j = 0; j < 4; ++j) {
            u[j] = M0[j] + __expf(0.5f * L0[j]) * E0[j];
            v[j] = M1[j] + __expf(0.5f * L1[j]) * E1[j];
        }
        u[4] = has_r ? (m0r + __expf(0.5f * l0r) * e0r) : 0.f;
        v[4] = has_r ? (m1r + __expf(0.5f * l1r) * e1r) : 0.f;
        if (has_d) {
            const float* A0 = &md0.x; const float* A1 = &md1.x;
            const float* B0 = &ld0.x; const float* B1 = &ld1.x;
            const float* C0 = &ed0.x; const float* C1 = &ed1.x;
            #pragma unroll
            for (int j = 0; j < 4; ++j) {
                ud[j] = A0[j] + __expf(0.5f * B0[j]) * C0[j];
                vd[j] = A1[j] + __expf(0.5f * B1[j]) * C1[j];
            }
        }
    }

    // ---- gather addresses for all 4 pixels (issue loads in one batch) ----
    int g00[4], g01[4], g10[4], g11[4];
    float wxv[4], wyv[4];
    #pragma unroll
    for (int j = 0; j < 4; ++j) {
        const float xs = (float)(x + j) + u[j];
        const float ys = (float)y + v[j];
        const float x0f = floorf(xs), y0f = floorf(ys);
        wxv[j] = xs - x0f;  wyv[j] = ys - y0f;
        int x0 = min(max((int)x0f, 0), WW - 1);
        const int x1 = min(x0 + 1, WW - 1);
        int y0 = min(max((int)y0f, 0), HH - 1);
        const int y1 = min(y0 + 1, HH - 1);
        g00[j] = y0 * WW + x0;  g01[j] = y0 * WW + x1;
        g10[j] = y1 * WW + x0;  g11[j] = y1 * WW + x1;
    }

    float se = 0.0f, sp = 0.0f;

    #pragma unroll
    for (int j = 0; j < 4; ++j) {
        // smoothness
        float dx2 = 0.0f, dy2 = 0.0f;
        if (j < 3 || has_r) {
            const float a = u[j + 1] - u[j], c = v[j + 1] - v[j];
            dx2 = a * a + c * c;
        }
        if (has_d) {
            const float a = ud[j] - u[j], c = vd[j] - v[j];
            dy2 = a * a + c * c;
        }
        const float smooth = sqrtf(dx2 + dy2 + 1e-5f);

        // data term: bilinear taps over 3 channels
        const float* I1[3] = { &i1c0.x, &i1c1.x, &i1c2.x };
        float A = 0.0f;
        #pragma unroll
        for (int c = 0; c < 3; ++c) {
            const int o = b3 + c * HW;
            const float v00 = img2[o + g00[j]];
            const float v01 = img2[o + g01[j]];
            const float v10 = img2[o + g10[j]];
            const float v11 = img2[o + g11[j]];
            const float top = v00 + wxv[j] * (v01 - v00);
            const float bot = v10 + wxv[j] * (v11 - v10);
            const float w   = top + wyv[j] * (bot - top);
            const float d   = I1[c][j] - w;
            A += d * d;
        }
        const float data = sqrtf(A + 1e-5f);

        // EPE
        const float du = (&m0.x)[j] - (&t0.x)[j];
        const float dv = (&m1.x)[j] - (&t1.x)[j];
        sp += sqrtf(du * du + dv * dv);

        se += data + smooth - 0.5f * ((&l0.x)[j] + (&l1.x)[j]);
    }

    // ---- block reduction: wave shuffle then LDS across 4 waves ----
    #pragma unroll
    for (int off = 32; off > 0; off >>= 1) {
        se += __shfl_down(se, off);
        sp += __shfl_down(sp, off);
    }
    __shared__ float s_e[NTHR / 64], s_p[NTHR / 64];
    const int lane = threadIdx.x & 63;
    const int wid  = threadIdx.x >> 6;
    if (lane == 0) { s_e[wid] = se; s_p[wid] = sp; }
    __syncthreads();
    if (threadIdx.x == 0) {
        float te = 0.0f, tp = 0.0f;
        #pragma unroll
        for (int i = 0; i < NTHR / 64; ++i) { te += s_e[i]; tp += s_p[i]; }
        partials[blockIdx.x] = make_float2(te, tp);
    }
}

__global__ __launch_bounds__(256) void elbo_final(
    const float2* __restrict__ partials, float* __restrict__ out)
{
    double se = 0.0, sp = 0.0;
    for (int i = threadIdx.x; i < NBLK; i += 256) {
        const float2 v = partials[i];
        se += (double)v.x;
        sp += (double)v.y;
    }
    #pragma unroll
    for (int off = 32; off > 0; off >>= 1) {
        se += __shfl_down(se, off);
        sp += __shfl_down(sp, off);
    }
    __shared__ double s_e[4], s_p[4];
    const int lane = threadIdx.x & 63;
    const int wid  = threadIdx.x >> 6;
    if (lane == 0) { s_e[wid] = se; s_p[wid] = sp; }
    __syncthreads();
    if (threadIdx.x == 0) {
        double te = 0.0, tp = 0.0;
        #pragma unroll
        for (int i = 0; i < 4; ++i) { te += s_e[i]; tp += s_p[i]; }
        out[0] = (float)(te / (double)BB);
        out[1] = (float)(tp / (double)TOTAL);
    }
}

extern "C" void kernel_launch(void* const* d_in, const int* in_sizes, int n_in,
                              void* d_out, int out_size, void* d_ws, size_t ws_size,
                              hipStream_t stream) {
    const float* mean   = (const float*)d_in[0];
    const float* logvar = (const float*)d_in[1];
    const float* img1   = (const float*)d_in[2];
    const float* img2   = (const float*)d_in[3];
    const float* target = (const float*)d_in[4];
    const float* eps    = (const float*)d_in[5];
    float* out = (float*)d_out;
    float2* partials = (float2*)d_ws;   // NBLK * 8 bytes = 57 KiB

    elbo_main<<<NBLK, NTHR, 0, stream>>>(mean, logvar, img1, img2, target, eps, partials);
    elbo_final<<<1, 256, 0, stream>>>(partials, out);
}